// Round 3
// baseline (1305.287 us; speedup 1.0000x reference)
//
#include <hip/hip_runtime.h>

// RNNBlock: h_t = relu(x_t @ W + h_{t-1} @ U + b) over reversed T, then
// out = relu(h @ W1 + b1).  B=65536, T=79, F=8, C=DW=256.
//
// R8 = R7 + halved LDS-read duplication (64 cols/wave, 4-wave blocks).
// R7 counter evidence: with measured DS costs (m134: b128 ~12cyc, b16 ~5cyc)
// the 5240-cyc step was ~83% LDS-pipe: reads 256xb128=3072 + writes 256x
// b16=1280.  Read traffic = (N/N_wave) x K x 2B per row -> duplication 8x.
// R8: wave owns 64 rows x 64 cols (2 B-frag sets bf[2][17]); 4 waves/block,
// 256 thr; LDS 64 KB/block -> 2 blocks/CU co-resident (8 waves/CU, 2/SIMD,
// independent barriers = natural phase stagger).  Reads/64-row step: 128
// b128 (1536 cyc), writes unchanged.  Projected step ~2800-3400 cyc.
//
// REGISTER PLAN (split law R2/R4 + gfx950 unified RF): waves_per_eu(2,2)
// budget 256/wave, even split V=128/A=128.  MFMA-only values (bf 136, acc
// 64) are av-class -> allocator places acc + ~64 bf regs in AGPR file;
// arch-V: ~72 bf + ~30 temps <= 128.  FAILURE SIGNATURE: dur regress +
// FETCH_SIZE balloon (scratch) -> revert to R7 + write-packing.
//
// LDS layout unchanged (R5-measured conflict-free, R7 XOR-separable):
//   byte(r,c) = (r&63)*512 + (((c>>3) ^ (r&31))<<4) + (c&7)*2
//   read  addr = rbase ^ (kf<<5),  rbase = (l31<<9)^(q<<4)^(l31<<4)
//                mf -> +16384 imm, buf -> +32768 imm
//   write addr = wb[nf] ^ Kg, Kg = (rr<<9)|(rr<<4) (rr bit2==0), mf ->
//                +16384 imm, buf -> +32768 imm
// Write banks: per instr 8 granules x 4 banks, 2 lanes/bank = 2-way = free.
//
// MFMA v_mfma_f32_32x32x16_f16 layouts (learn_hip verified):
//   A[m][k]: m = lane&31, k = 8*(lane>>5) + j
//   B[k][n]: k = 8*(lane>>5) + j, n = lane&31
//   C/D    : col = lane&31, row = (reg&3) + 8*(reg>>2) + 4*(lane>>5)

#define B_ROWS 65536
#define T_STEPS 79
#define F_IN 8
#define C_DIM 256

typedef _Float16 h16;
typedef __attribute__((ext_vector_type(8))) _Float16 half8;
typedef __attribute__((ext_vector_type(16))) float f32x16;
typedef __attribute__((ext_vector_type(4))) float f32x4;

// B-fragments (both 32-col halves) of the 272x256 augmented weight.
// rows 0..255 = M (U or W1), 256..263 = Wx (or 0), 264 = bias, 265..271 = 0.
// nf-half n-col = ncol0 + 32*nf.
__device__ __forceinline__ void load_bfrags(half8 bf[2][17],
                                            const float* __restrict__ M,
                                            const float* __restrict__ Wx,
                                            const float* __restrict__ bias,
                                            int ncol0, int q) {
  #pragma unroll
  for (int nf = 0; nf < 2; ++nf) {
    const int n = ncol0 + 32 * nf;
    #pragma unroll
    for (int kf = 0; kf < 16; ++kf) {
      const int k0 = 16 * kf + 8 * q;
      half8 v;
      #pragma unroll
      for (int j = 0; j < 8; ++j)
        v[j] = (h16)M[(size_t)(k0 + j) * C_DIM + n];
      bf[nf][kf] = v;
    }
    half8 v;
    #pragma unroll
    for (int j = 0; j < 8; ++j) v[j] = (h16)0.f;
    if (q == 0) {
      if (Wx) {
        #pragma unroll
        for (int j = 0; j < 8; ++j) v[j] = (h16)Wx[j * C_DIM + n];
      }
    } else {
      v[0] = (h16)bias[n];  // k=264 pairs with A-side constant 1.0
    }
    bf[nf][16] = v;
  }
}

// ---- per-step building blocks (macros so all LDS offsets are immediates) ---

// issue global x loads (q==0 lanes), advance to previous t
#define LOAD_X(lo, hi)                                                      \
  f32x4 lo[2], hi[2];                                                       \
  if (q == 0) {                                                             \
    _Pragma("unroll") for (int mf = 0; mf < 2; ++mf) {                      \
      const f32x4* xp = (const f32x4*)(xbase + xoff[mf]);                   \
      lo[mf] = xp[0];                                                       \
      hi[mf] = xp[1];                                                       \
      xoff[mf] -= F_IN * 4;                                                 \
    }                                                                       \
  }

#define MAKE_XA(xa, lo, hi)                                                 \
  half8 xa[2];                                                              \
  _Pragma("unroll") for (int mf = 0; mf < 2; ++mf) {                        \
    if (q == 0) {                                                           \
      half8 v;                                                              \
      v[0] = (h16)lo[mf][0]; v[1] = (h16)lo[mf][1];                         \
      v[2] = (h16)lo[mf][2]; v[3] = (h16)lo[mf][3];                         \
      v[4] = (h16)hi[mf][0]; v[5] = (h16)hi[mf][1];                         \
      v[6] = (h16)hi[mf][2]; v[7] = (h16)hi[mf][3];                         \
      xa[mf] = v;                                                           \
    } else {                                                                \
      half8 v;                                                              \
      _Pragma("unroll") for (int j = 0; j < 8; ++j) v[j] = (h16)0.f;        \
      v[0] = (h16)1.f; /* bias partner */                                   \
      xa[mf] = v;                                                           \
    }                                                                       \
  }

// write h (relu, fp16) into buffer WB; wb[nf] ^ const + offset immediates.
// acc naming: aMN = rows 32*M.., cols 32*N..
#define EPILOGUE(a00, a01, a10, a11, WB)                                    \
  _Pragma("unroll") for (int g = 0; g < 16; ++g) {                          \
    const int rr_g = (g & 3) + ((g >> 2) << 3);                             \
    const int Kg = (rr_g << 9) | (rr_g << 4);                               \
    char* const wp0 = lds + (wb0 ^ Kg);                                     \
    char* const wp1 = lds + (wb1 ^ Kg);                                     \
    *(h16*)(wp0 + (WB) * 32768) = (h16)fmaxf(a00[g], 0.f);                  \
    *(h16*)(wp0 + (WB) * 32768 + 16384) = (h16)fmaxf(a10[g], 0.f);          \
    *(h16*)(wp1 + (WB) * 32768) = (h16)fmaxf(a01[g], 0.f);                  \
    *(h16*)(wp1 + (WB) * 32768 + 16384) = (h16)fmaxf(a11[g], 0.f);          \
  }

#define STEP(RBUF)                                                          \
  do {                                                                      \
    LOAD_X(lo_, hi_);                                                       \
    __syncthreads(); /* h(s-1) writes visible; hides x-load latency */      \
    MAKE_XA(xa_, lo_, hi_);                                                 \
    f32x16 a00_ = __builtin_amdgcn_mfma_f32_32x32x16_f16(                   \
        xa_[0], bf[0][16], (f32x16)(0.f), 0, 0, 0);                         \
    f32x16 a01_ = __builtin_amdgcn_mfma_f32_32x32x16_f16(                   \
        xa_[0], bf[1][16], (f32x16)(0.f), 0, 0, 0);                         \
    f32x16 a10_ = __builtin_amdgcn_mfma_f32_32x32x16_f16(                   \
        xa_[1], bf[0][16], (f32x16)(0.f), 0, 0, 0);                         \
    f32x16 a11_ = __builtin_amdgcn_mfma_f32_32x32x16_f16(                   \
        xa_[1], bf[1][16], (f32x16)(0.f), 0, 0, 0);                         \
    _Pragma("unroll") for (int kf = 0; kf < 16; ++kf) {                     \
      const char* const rp = lds + (rbase ^ (kf << 5));                     \
      const half8 f0_ = *(const half8*)(rp + (RBUF)*32768);                 \
      a00_ = __builtin_amdgcn_mfma_f32_32x32x16_f16(f0_, bf[0][kf], a00_,   \
                                                    0, 0, 0);               \
      a01_ = __builtin_amdgcn_mfma_f32_32x32x16_f16(f0_, bf[1][kf], a01_,   \
                                                    0, 0, 0);               \
      const half8 f1_ = *(const half8*)(rp + (RBUF)*32768 + 16384);         \
      a10_ = __builtin_amdgcn_mfma_f32_32x32x16_f16(f1_, bf[0][kf], a10_,   \
                                                    0, 0, 0);               \
      a11_ = __builtin_amdgcn_mfma_f32_32x32x16_f16(f1_, bf[1][kf], a11_,   \
                                                    0, 0, 0);               \
    }                                                                       \
    EPILOGUE(a00_, a01_, a10_, a11_, (RBUF) ^ 1);                           \
  } while (0)

__global__ __launch_bounds__(256)
__attribute__((amdgpu_waves_per_eu(2, 2)))
void rnn_fused(const float* __restrict__ x, const float* __restrict__ W,
               const float* __restrict__ U, const float* __restrict__ b,
               const float* __restrict__ W1, const float* __restrict__ b1,
               float* __restrict__ out) {
  __shared__ alignas(16) h16 hbuf[2][64 * 256];  // 2 x 32 KB

  const int tid = threadIdx.x;
  const int lane = tid & 63;
  const int wave = tid >> 6;        // 0..3, owns cols [64w, 64w+64)
  const int l31 = lane & 31;
  const int q = lane >> 5;
  const int row0 = blockIdx.x << 6; // 64 batch rows per block
  const int ncol0 = (wave << 6) + l31;  // nf=0 column; nf=1 = +32

  half8 bf[2][17];
  load_bfrags(bf, U, W, b, ncol0, q);

  char* const lds = (char*)hbuf;

  // XOR-separable base addresses (see header comment)
  const int rbase = (l31 << 9) ^ (q << 4) ^ (l31 << 4);
  const int wb0 = (q << 11) ^ (q << 6) ^ ((ncol0 >> 3) << 4) ^
                  ((ncol0 & 7) << 1);
  const int wb1 = (q << 11) ^ (q << 6) ^ (((ncol0 + 32) >> 3) << 4) ^
                  ((ncol0 & 7) << 1);

  const char* const xbase = (const char*)x;
  int xoff[2];
  #pragma unroll
  for (int mf = 0; mf < 2; ++mf)
    xoff[mf] = ((row0 + (mf << 5) + l31) * (T_STEPS * F_IN) +
                (T_STEPS - 1) * F_IN)
               << 2;

  // ---- s = 0 (t = 78): h0 = 0, no LDS read, writes buf1, no barrier ----
  {
    LOAD_X(lo_, hi_);
    MAKE_XA(xa_, lo_, hi_);
    f32x16 a00_ = __builtin_amdgcn_mfma_f32_32x32x16_f16(
        xa_[0], bf[0][16], (f32x16)(0.f), 0, 0, 0);
    f32x16 a01_ = __builtin_amdgcn_mfma_f32_32x32x16_f16(
        xa_[0], bf[1][16], (f32x16)(0.f), 0, 0, 0);
    f32x16 a10_ = __builtin_amdgcn_mfma_f32_32x32x16_f16(
        xa_[1], bf[0][16], (f32x16)(0.f), 0, 0, 0);
    f32x16 a11_ = __builtin_amdgcn_mfma_f32_32x32x16_f16(
        xa_[1], bf[1][16], (f32x16)(0.f), 0, 0, 0);
    EPILOGUE(a00_, a01_, a10_, a11_, 1);
  }

  // ---- s = 1..78 as 39 unrolled pairs: odd s reads buf1, even s buf0 ----
  #pragma unroll 1
  for (int sp = 0; sp < (T_STEPS - 1) / 2; ++sp) {
    STEP(1);
    STEP(0);
  }
  // last step (s=78, even) read buf0 and wrote h(final) into buf1

  // ---- final Dense(256, relu): same GEMM with W1/b1, x rows zeroed ----
  load_bfrags(bf, W1, nullptr, b1, ncol0, q);
  half8 xaf;
  #pragma unroll
  for (int j = 0; j < 8; ++j) xaf[j] = (h16)0.f;
  if (q == 1) xaf[0] = (h16)1.f;

  f32x16 a00 = __builtin_amdgcn_mfma_f32_32x32x16_f16(
      xaf, bf[0][16], (f32x16)(0.f), 0, 0, 0);
  f32x16 a01 = __builtin_amdgcn_mfma_f32_32x32x16_f16(
      xaf, bf[1][16], (f32x16)(0.f), 0, 0, 0);
  f32x16 a10 = __builtin_amdgcn_mfma_f32_32x32x16_f16(
      xaf, bf[0][16], (f32x16)(0.f), 0, 0, 0);
  f32x16 a11 = __builtin_amdgcn_mfma_f32_32x32x16_f16(
      xaf, bf[1][16], (f32x16)(0.f), 0, 0, 0);

  __syncthreads();  // h(final) writes visible in buf1

  #pragma unroll
  for (int kf = 0; kf < 16; ++kf) {
    const char* const rp = lds + (rbase ^ (kf << 5));
    const half8 f0 = *(const half8*)(rp + 32768);
    a00 = __builtin_amdgcn_mfma_f32_32x32x16_f16(f0, bf[0][kf], a00, 0, 0, 0);
    a01 = __builtin_amdgcn_mfma_f32_32x32x16_f16(f0, bf[1][kf], a01, 0, 0, 0);
    const half8 f1 = *(const half8*)(rp + 32768 + 16384);
    a10 = __builtin_amdgcn_mfma_f32_32x32x16_f16(f1, bf[0][kf], a10, 0, 0, 0);
    a11 = __builtin_amdgcn_mfma_f32_32x32x16_f16(f1, bf[1][kf], a11, 0, 0, 0);
  }

  #pragma unroll
  for (int g = 0; g < 16; ++g) {
    const int rr = (g & 3) + ((g >> 2) << 3) + (q << 2);
    out[(size_t)(row0 + rr) * C_DIM + ncol0] = fmaxf(a00[g], 0.f);
    out[(size_t)(row0 + rr) * C_DIM + ncol0 + 32] = fmaxf(a01[g], 0.f);
    out[(size_t)(row0 + 32 + rr) * C_DIM + ncol0] = fmaxf(a10[g], 0.f);
    out[(size_t)(row0 + 32 + rr) * C_DIM + ncol0 + 32] = fmaxf(a11[g], 0.f);
  }
}

extern "C" void kernel_launch(void* const* d_in, const int* in_sizes, int n_in,
                              void* d_out, int out_size, void* d_ws,
                              size_t ws_size, hipStream_t stream) {
  const float* x  = (const float*)d_in[0];
  const float* W  = (const float*)d_in[1];
  const float* U  = (const float*)d_in[2];
  const float* b  = (const float*)d_in[3];
  const float* W1 = (const float*)d_in[4];
  const float* b1 = (const float*)d_in[5];
  float* out = (float*)d_out;

  rnn_fused<<<B_ROWS / 64, 256, 0, stream>>>(x, W, U, b, W1, b1, out);
}

// Round 5
// 1181.614 us; speedup vs baseline: 1.1047x; 1.1047x over previous
//
#include <hip/hip_runtime.h>

// RNNBlock: h_t = relu(x_t @ W + h_{t-1} @ U + b) over reversed T, then
// out = relu(h @ W1 + b1).  B=65536, T=79, F=8, C=DW=256.
//
// R10 = R9 resubmission (R9 hit an infra "container failed twice", never
// measured; paper re-audit found no correctness or hang hazard).
// R9 = R8's Cw=4 structure (64 cols/wave, halved LDS-read duplication) with
// the register cap LIFTED via waves_per_eu(1,1) instead of (2,2).
// R8 post-mortem: (2,2) => V=128 arch cap; allocator did NOT place the
// bf[2][17]=136 MFMA-only frags in AGPRs -> scratch spill (FETCH 92->282MB,
// WRITE 65->596MB, dur 1240us). (1,1) => budget 512, V=256/A=256: bf 136 +
// acc 64 + temps fit with 2x headroom.
// Occupancy: 1 wave/SIMD (4 waves/CU, 1 block/CU, 64KB LDS). To survive
// no-TLP: x is prefetched ONE FULL STEP ahead (issued top-of-step, consumed
// next step), so HBM latency hides under the ~2900cyc compute phase.
//
// Per-CU-step budget (m134 DS costs): reads 128 b128 = 1536 cyc (was 3072),
// writes 256 b16 = 1280, LDS pipe ~2816; MFMA 272/CU = 2176 cyc/SIMD-pipe;
// VALU ~400 cyc/SIMD (1 wave).  Projected step ~2900-3400 cyc -> ~430-510us.
//
// LDS layout unchanged (R5-measured conflict-free, R7 XOR-separable):
//   byte(r,c) = (r&63)*512 + (((c>>3) ^ (r&31))<<4) + (c&7)*2
//   read  addr = rbase ^ (kf<<5),  rbase = (l31<<9)^(q<<4)^(l31<<4)
//                mf -> +16384 imm, buf -> +32768 imm
//   write addr = wb[nf] ^ Kg, Kg = (rr<<9)|(rr<<4), mf -> +16384 imm
//
// MFMA v_mfma_f32_32x32x16_f16 layouts (learn_hip verified):
//   A[m][k]: m = lane&31, k = 8*(lane>>5) + j
//   B[k][n]: k = 8*(lane>>5) + j, n = lane&31
//   C/D    : col = lane&31, row = (reg&3) + 8*(reg>>2) + 4*(lane>>5)

#define B_ROWS 65536
#define T_STEPS 79
#define F_IN 8
#define C_DIM 256

typedef _Float16 h16;
typedef __attribute__((ext_vector_type(8))) _Float16 half8;
typedef __attribute__((ext_vector_type(16))) float f32x16;
typedef __attribute__((ext_vector_type(4))) float f32x4;

// B-fragments (both 32-col halves) of the 272x256 augmented weight.
// rows 0..255 = M (U or W1), 256..263 = Wx (or 0), 264 = bias, 265..271 = 0.
__device__ __forceinline__ void load_bfrags(half8 bf[2][17],
                                            const float* __restrict__ M,
                                            const float* __restrict__ Wx,
                                            const float* __restrict__ bias,
                                            int ncol0, int q) {
  #pragma unroll
  for (int nf = 0; nf < 2; ++nf) {
    const int n = ncol0 + 32 * nf;
    #pragma unroll
    for (int kf = 0; kf < 16; ++kf) {
      const int k0 = 16 * kf + 8 * q;
      half8 v;
      #pragma unroll
      for (int j = 0; j < 8; ++j)
        v[j] = (h16)M[(size_t)(k0 + j) * C_DIM + n];
      bf[nf][kf] = v;
    }
    half8 v;
    #pragma unroll
    for (int j = 0; j < 8; ++j) v[j] = (h16)0.f;
    if (q == 0) {
      if (Wx) {
        #pragma unroll
        for (int j = 0; j < 8; ++j) v[j] = (h16)Wx[j * C_DIM + n];
      }
    } else {
      v[0] = (h16)bias[n];  // k=264 pairs with A-side constant 1.0
    }
    bf[nf][16] = v;
  }
}

// ---- per-step building blocks (macros so all LDS offsets are immediates) ---

// issue global x loads for the NEXT step (q==0 lanes); uniform toff walks
// t backwards, scalar-clamped at 0 (last prefetch harmlessly re-reads t=0).
#define LOADX(l0, h0, l1, h1)                                               \
  if (q == 0) {                                                             \
    l0 = *(const f32x4*)(xbase + rowoff0 + toff);                           \
    h0 = *(const f32x4*)(xbase + rowoff0 + toff + 16);                      \
    l1 = *(const f32x4*)(xbase + rowoff1 + toff);                           \
    h1 = *(const f32x4*)(xbase + rowoff1 + toff + 16);                      \
  }                                                                         \
  toff -= F_IN * 4;                                                         \
  if (toff < 0) toff = 0;

#define MAKE_XA2(xa)                                                        \
  half8 xa[2];                                                              \
  if (q == 0) {                                                             \
    half8 v0, v1;                                                           \
    v0[0] = (h16)cl0[0]; v0[1] = (h16)cl0[1];                               \
    v0[2] = (h16)cl0[2]; v0[3] = (h16)cl0[3];                               \
    v0[4] = (h16)ch0[0]; v0[5] = (h16)ch0[1];                               \
    v0[6] = (h16)ch0[2]; v0[7] = (h16)ch0[3];                               \
    v1[0] = (h16)cl1[0]; v1[1] = (h16)cl1[1];                               \
    v1[2] = (h16)cl1[2]; v1[3] = (h16)cl1[3];                               \
    v1[4] = (h16)ch1[0]; v1[5] = (h16)ch1[1];                               \
    v1[6] = (h16)ch1[2]; v1[7] = (h16)ch1[3];                               \
    xa[0] = v0;                                                             \
    xa[1] = v1;                                                             \
  } else {                                                                  \
    half8 v;                                                                \
    _Pragma("unroll") for (int j = 0; j < 8; ++j) v[j] = (h16)0.f;          \
    v[0] = (h16)1.f; /* bias partner */                                     \
    xa[0] = v;                                                              \
    xa[1] = v;                                                              \
  }

// write h (relu, fp16) into buffer WB; wb[nf] ^ const + offset immediates.
// acc naming: aMN = rows 32*M.., cols 32*N..
#define EPILOGUE(a00, a01, a10, a11, WB)                                    \
  _Pragma("unroll") for (int g = 0; g < 16; ++g) {                          \
    const int rr_g = (g & 3) + ((g >> 2) << 3);                             \
    const int Kg = (rr_g << 9) | (rr_g << 4);                               \
    char* const wp0 = lds + (wb0 ^ Kg);                                     \
    char* const wp1 = lds + (wb1 ^ Kg);                                     \
    *(h16*)(wp0 + (WB) * 32768) = (h16)fmaxf(a00[g], 0.f);                  \
    *(h16*)(wp0 + (WB) * 32768 + 16384) = (h16)fmaxf(a10[g], 0.f);          \
    *(h16*)(wp1 + (WB) * 32768) = (h16)fmaxf(a01[g], 0.f);                  \
    *(h16*)(wp1 + (WB) * 32768 + 16384) = (h16)fmaxf(a11[g], 0.f);          \
  }

#define STEP(RBUF)                                                          \
  do {                                                                      \
    f32x4 nl0, nh0, nl1, nh1;                                               \
    LOADX(nl0, nh0, nl1, nh1); /* prefetch step s+1 */                      \
    __syncthreads(); /* h(s-1) writes visible */                            \
    MAKE_XA2(xa_);                                                          \
    f32x16 a00_ = __builtin_amdgcn_mfma_f32_32x32x16_f16(                   \
        xa_[0], bf[0][16], (f32x16)(0.f), 0, 0, 0);                         \
    f32x16 a01_ = __builtin_amdgcn_mfma_f32_32x32x16_f16(                   \
        xa_[0], bf[1][16], (f32x16)(0.f), 0, 0, 0);                         \
    f32x16 a10_ = __builtin_amdgcn_mfma_f32_32x32x16_f16(                   \
        xa_[1], bf[0][16], (f32x16)(0.f), 0, 0, 0);                         \
    f32x16 a11_ = __builtin_amdgcn_mfma_f32_32x32x16_f16(                   \
        xa_[1], bf[1][16], (f32x16)(0.f), 0, 0, 0);                         \
    _Pragma("unroll") for (int kf = 0; kf < 16; ++kf) {                     \
      const char* const rp = lds + (rbase ^ (kf << 5));                     \
      const half8 f0_ = *(const half8*)(rp + (RBUF)*32768);                 \
      a00_ = __builtin_amdgcn_mfma_f32_32x32x16_f16(f0_, bf[0][kf], a00_,   \
                                                    0, 0, 0);               \
      a01_ = __builtin_amdgcn_mfma_f32_32x32x16_f16(f0_, bf[1][kf], a01_,   \
                                                    0, 0, 0);               \
      const half8 f1_ = *(const half8*)(rp + (RBUF)*32768 + 16384);         \
      a10_ = __builtin_amdgcn_mfma_f32_32x32x16_f16(f1_, bf[0][kf], a10_,   \
                                                    0, 0, 0);               \
      a11_ = __builtin_amdgcn_mfma_f32_32x32x16_f16(f1_, bf[1][kf], a11_,   \
                                                    0, 0, 0);               \
    }                                                                       \
    EPILOGUE(a00_, a01_, a10_, a11_, (RBUF) ^ 1);                           \
    cl0 = nl0; ch0 = nh0; cl1 = nl1; ch1 = nh1;                             \
  } while (0)

__global__ __launch_bounds__(256)
__attribute__((amdgpu_waves_per_eu(1, 1)))
void rnn_fused(const float* __restrict__ x, const float* __restrict__ W,
               const float* __restrict__ U, const float* __restrict__ b,
               const float* __restrict__ W1, const float* __restrict__ b1,
               float* __restrict__ out) {
  __shared__ alignas(16) h16 hbuf[2][64 * 256];  // 2 x 32 KB

  const int tid = threadIdx.x;
  const int lane = tid & 63;
  const int wave = tid >> 6;        // 0..3, owns cols [64w, 64w+64)
  const int l31 = lane & 31;
  const int q = lane >> 5;
  const int row0 = blockIdx.x << 6; // 64 batch rows per block
  const int ncol0 = (wave << 6) + l31;  // nf=0 column; nf=1 = +32

  half8 bf[2][17];
  load_bfrags(bf, U, W, b, ncol0, q);

  char* const lds = (char*)hbuf;

  // XOR-separable base addresses (see header comment)
  const int rbase = (l31 << 9) ^ (q << 4) ^ (l31 << 4);
  const int wb0 = (q << 11) ^ (q << 6) ^ ((ncol0 >> 3) << 4) ^
                  ((ncol0 & 7) << 1);
  const int wb1 = (q << 11) ^ (q << 6) ^ (((ncol0 + 32) >> 3) << 4) ^
                  ((ncol0 & 7) << 1);

  const char* const xbase = (const char*)x;
  const int rowoff0 = (row0 + l31) * (T_STEPS * F_IN) * 4;
  const int rowoff1 = (row0 + 32 + l31) * (T_STEPS * F_IN) * 4;
  int toff = (T_STEPS - 1) * F_IN * 4;  // uniform t byte offset, walks down

  // current x regs (loaded, not yet consumed)
  f32x4 cl0, ch0, cl1, ch1;

  // prologue: load x(s=0) (t=78)
  LOADX(cl0, ch0, cl1, ch1);

  // ---- s = 0 (t = 78): h0 = 0, no LDS read, writes buf1, no barrier ----
  {
    f32x4 nl0, nh0, nl1, nh1;
    LOADX(nl0, nh0, nl1, nh1);  // prefetch x(s=1)
    MAKE_XA2(xa_);
    f32x16 a00_ = __builtin_amdgcn_mfma_f32_32x32x16_f16(
        xa_[0], bf[0][16], (f32x16)(0.f), 0, 0, 0);
    f32x16 a01_ = __builtin_amdgcn_mfma_f32_32x32x16_f16(
        xa_[0], bf[1][16], (f32x16)(0.f), 0, 0, 0);
    f32x16 a10_ = __builtin_amdgcn_mfma_f32_32x32x16_f16(
        xa_[1], bf[0][16], (f32x16)(0.f), 0, 0, 0);
    f32x16 a11_ = __builtin_amdgcn_mfma_f32_32x32x16_f16(
        xa_[1], bf[1][16], (f32x16)(0.f), 0, 0, 0);
    EPILOGUE(a00_, a01_, a10_, a11_, 1);
    cl0 = nl0; ch0 = nh0; cl1 = nl1; ch1 = nh1;
  }

  // ---- s = 1..78 as 39 unrolled pairs: odd s reads buf1, even s buf0 ----
  #pragma unroll 1
  for (int sp = 0; sp < (T_STEPS - 1) / 2; ++sp) {
    STEP(1);
    STEP(0);
  }
  // last step (s=78, even) read buf0 and wrote h(final) into buf1

  // ---- final Dense(256, relu): same GEMM with W1/b1, x rows zeroed ----
  load_bfrags(bf, W1, nullptr, b1, ncol0, q);
  half8 xaf;
  #pragma unroll
  for (int j = 0; j < 8; ++j) xaf[j] = (h16)0.f;
  if (q == 1) xaf[0] = (h16)1.f;

  f32x16 a00 = __builtin_amdgcn_mfma_f32_32x32x16_f16(
      xaf, bf[0][16], (f32x16)(0.f), 0, 0, 0);
  f32x16 a01 = __builtin_amdgcn_mfma_f32_32x32x16_f16(
      xaf, bf[1][16], (f32x16)(0.f), 0, 0, 0);
  f32x16 a10 = __builtin_amdgcn_mfma_f32_32x32x16_f16(
      xaf, bf[0][16], (f32x16)(0.f), 0, 0, 0);
  f32x16 a11 = __builtin_amdgcn_mfma_f32_32x32x16_f16(
      xaf, bf[1][16], (f32x16)(0.f), 0, 0, 0);

  __syncthreads();  // h(final) writes visible in buf1

  #pragma unroll
  for (int kf = 0; kf < 16; ++kf) {
    const char* const rp = lds + (rbase ^ (kf << 5));
    const half8 f0 = *(const half8*)(rp + 32768);
    a00 = __builtin_amdgcn_mfma_f32_32x32x16_f16(f0, bf[0][kf], a00, 0, 0, 0);
    a01 = __builtin_amdgcn_mfma_f32_32x32x16_f16(f0, bf[1][kf], a01, 0, 0, 0);
    const half8 f1 = *(const half8*)(rp + 32768 + 16384);
    a10 = __builtin_amdgcn_mfma_f32_32x32x16_f16(f1, bf[0][kf], a10, 0, 0, 0);
    a11 = __builtin_amdgcn_mfma_f32_32x32x16_f16(f1, bf[1][kf], a11, 0, 0, 0);
  }

  #pragma unroll
  for (int g = 0; g < 16; ++g) {
    const int rr = (g & 3) + ((g >> 2) << 3) + (q << 2);
    out[(size_t)(row0 + rr) * C_DIM + ncol0] = fmaxf(a00[g], 0.f);
    out[(size_t)(row0 + rr) * C_DIM + ncol0 + 32] = fmaxf(a01[g], 0.f);
    out[(size_t)(row0 + 32 + rr) * C_DIM + ncol0] = fmaxf(a10[g], 0.f);
    out[(size_t)(row0 + 32 + rr) * C_DIM + ncol0 + 32] = fmaxf(a11[g], 0.f);
  }
}

extern "C" void kernel_launch(void* const* d_in, const int* in_sizes, int n_in,
                              void* d_out, int out_size, void* d_ws,
                              size_t ws_size, hipStream_t stream) {
  const float* x  = (const float*)d_in[0];
  const float* W  = (const float*)d_in[1];
  const float* U  = (const float*)d_in[2];
  const float* b  = (const float*)d_in[3];
  const float* W1 = (const float*)d_in[4];
  const float* b1 = (const float*)d_in[5];
  float* out = (float*)d_out;

  rnn_fused<<<B_ROWS / 64, 256, 0, stream>>>(x, W, U, b, W1, b1, out);
}

// Round 9
// 819.886 us; speedup vs baseline: 1.5920x; 1.4412x over previous
//
#include <hip/hip_runtime.h>

// RNNBlock: h_t = relu(x_t @ W + h_{t-1} @ U + b) over reversed T, then
// out = relu(h @ W1 + b1).  B=65536, T=79, F=8, C=DW=256.
//
// R14 = R13 resubmission (R13 hit infra "container failed twice", never
// measured) with one hardening: deprecated __builtin_amdgcn_mov_dpp ->
// __builtin_amdgcn_update_dpp (current builtin, rocPRIM-standard; compiler
// still owns the VALU->DPP hazard wait-states, unlike inline asm).
//
// R13 = R7 (690us verified) + packed b32 LDS writes in the epilogue.
// R7 counters re-derived: per-CU dual-block step 10487 cyc; DS pipe = 512
// ds_read_b128 x12 + 512 ds_write_b16 x5.8 = 9114 cyc = 87% busy -> DS-bound.
// (MfmaUtil 50% is occupancy-weighted pass cycles; true matrix-pipe ~10-20%.)
// b16 and b32 DS writes cost the same per INSTRUCTION (~5.8cyc, m134), so
// packing 2 adjacent-col fp16 into one b32 halves write instructions:
// 512->256/dual-step, DS 9114->7628.  Reads can't shrink without Nw=64
// (136 weight regs: R8 spill / R10 no-TLP / R11-R12 asm corruption -> dead).
//
// Packing: adjacent cols live in adjacent lanes -> DPP quad_perm[1,0,3,2]
// pair exchange (VALU, no LDS).  Parity row-split keeps 64 lanes writing:
// even lane packs rows rr_G (cols n,n+1), odd lane rows rr_G+16 (cols
// n-1,n), G=0..7; RTE rounding (cvt per element) kept for numerics.
//
// Write addressing stays XOR-separable; parity folds into the base:
//   wpk = (q<<11)^(q<<6)^(par<<13)^(par<<8)^((n>>3)<<4)^((n&6)<<1)
//   addr = wpk ^ KG, KG = (rrG<<9)|(rrG<<4); mf -> +16384, buf -> +32768.
// All field bits disjoint (row 9..13, granule 4..8, byte 1..3) - verified
// lane-by-lane.  Banks per instr: even/odd pair -> same bank (2-way, free
// m136); q=1 flips granule bit2 -> complementary 16-bank half.
//
// LDS layout / reads unchanged (R5-measured conflict-free, R7 XOR-sep):
//   byte(r,c) = (r&63)*512 + (((c>>3) ^ (r&31))<<4) + (c&7)*2
//   read addr = rbase ^ (kf<<5), rbase = (l31<<9)^(q<<4)^(l31<<4)
//
// MFMA v_mfma_f32_32x32x16_f16 layouts (learn_hip verified):
//   A[m][k]: m = lane&31, k = 8*(lane>>5) + j
//   B[k][n]: k = 8*(lane>>5) + j, n = lane&31
//   C/D    : col = lane&31, row = (reg&3) + 8*(reg>>2) + 4*(lane>>5)

#define B_ROWS 65536
#define T_STEPS 79
#define F_IN 8
#define C_DIM 256

typedef _Float16 h16;
typedef __attribute__((ext_vector_type(2))) _Float16 h16x2;
typedef __attribute__((ext_vector_type(8))) _Float16 half8;
typedef __attribute__((ext_vector_type(16))) float f32x16;
typedef __attribute__((ext_vector_type(4))) float f32x4;

// pair-swap within lane pairs (2m <-> 2m+1) via DPP quad_perm [1,0,3,2]
__device__ __forceinline__ float dpp_pairswap(float v) {
  const int iv = __builtin_bit_cast(int, v);
  return __builtin_bit_cast(
      float, __builtin_amdgcn_update_dpp(iv, iv, 0xB1, 0xF, 0xF, true));
}

// B-fragments for the 272x256 augmented weight, this wave's column n.
// rows 0..255 = M (U or W1), 256..263 = Wx (or 0), 264 = bias, 265..271 = 0.
__device__ __forceinline__ void load_bfrags(half8 bf[17],
                                            const float* __restrict__ M,
                                            const float* __restrict__ Wx,
                                            const float* __restrict__ bias,
                                            int n, int q) {
  #pragma unroll
  for (int kf = 0; kf < 16; ++kf) {
    const int k0 = 16 * kf + 8 * q;
    half8 v;
    #pragma unroll
    for (int j = 0; j < 8; ++j)
      v[j] = (h16)M[(size_t)(k0 + j) * C_DIM + n];
    bf[kf] = v;
  }
  half8 v;
  #pragma unroll
  for (int j = 0; j < 8; ++j) v[j] = (h16)0.f;
  if (q == 0) {
    if (Wx) {
      #pragma unroll
      for (int j = 0; j < 8; ++j) v[j] = (h16)Wx[j * C_DIM + n];
    }
  } else {
    v[0] = (h16)bias[n];  // k=264 pairs with A-side constant 1.0
  }
  bf[16] = v;
}

// ---- per-step building blocks (macros so all LDS offsets are immediates) ---

// issue global x loads (q==0 lanes), advance to previous t
#define LOAD_X(lo, hi)                                                      \
  f32x4 lo[2], hi[2];                                                       \
  if (q == 0) {                                                             \
    _Pragma("unroll") for (int mf = 0; mf < 2; ++mf) {                      \
      const f32x4* xp = (const f32x4*)(xbase + xoff[mf]);                   \
      lo[mf] = xp[0];                                                       \
      hi[mf] = xp[1];                                                       \
      xoff[mf] -= F_IN * 4;                                                 \
    }                                                                       \
  }

#define MAKE_XA(xa, lo, hi)                                                 \
  half8 xa[2];                                                              \
  _Pragma("unroll") for (int mf = 0; mf < 2; ++mf) {                        \
    if (q == 0) {                                                           \
      half8 v;                                                              \
      v[0] = (h16)lo[mf][0]; v[1] = (h16)lo[mf][1];                         \
      v[2] = (h16)lo[mf][2]; v[3] = (h16)lo[mf][3];                         \
      v[4] = (h16)hi[mf][0]; v[5] = (h16)hi[mf][1];                         \
      v[6] = (h16)hi[mf][2]; v[7] = (h16)hi[mf][3];                         \
      xa[mf] = v;                                                           \
    } else {                                                                \
      half8 v;                                                              \
      _Pragma("unroll") for (int j = 0; j < 8; ++j) v[j] = (h16)0.f;        \
      v[0] = (h16)1.f; /* bias partner */                                   \
      xa[mf] = v;                                                           \
    }                                                                       \
  }

// Packed-b32 epilogue: relu -> pair-exchange (DPP) -> h16x2 -> one b32 write
// per (G, mf).  Even lane handles rows rr_G, odd lane rows rr_G+16.
#define EPILOGUE(acc0, acc1, WB)                                            \
  _Pragma("unroll") for (int G = 0; G < 8; ++G) {                           \
    const int rrG = (G & 3) + ((G >> 2) << 3);                              \
    const int KG = (rrG << 9) | (rrG << 4);                                 \
    char* const wp = lds + (wpk ^ KG) + (WB)*32768;                         \
    {                                                                       \
      const float o0 = fmaxf(acc0[G], 0.f);                                 \
      const float o8 = fmaxf(acc0[G + 8], 0.f);                             \
      const float d0 = dpp_pairswap(o0);                                    \
      const float d8 = dpp_pairswap(o8);                                    \
      h16x2 pv;                                                             \
      pv[0] = (h16)(par ? d8 : o0);                                         \
      pv[1] = (h16)(par ? o8 : d0);                                         \
      *(h16x2*)wp = pv;                                                     \
    }                                                                       \
    {                                                                       \
      const float o0 = fmaxf(acc1[G], 0.f);                                 \
      const float o8 = fmaxf(acc1[G + 8], 0.f);                             \
      const float d0 = dpp_pairswap(o0);                                    \
      const float d8 = dpp_pairswap(o8);                                    \
      h16x2 pv;                                                             \
      pv[0] = (h16)(par ? d8 : o0);                                         \
      pv[1] = (h16)(par ? o8 : d0);                                         \
      *(h16x2*)(wp + 16384) = pv;                                           \
    }                                                                       \
  }

#define STEP(RBUF)                                                          \
  do {                                                                      \
    LOAD_X(lo_, hi_);                                                       \
    __syncthreads(); /* h(s-1) writes visible; hides x-load latency */      \
    MAKE_XA(xa_, lo_, hi_);                                                 \
    f32x16 acc0_ = __builtin_amdgcn_mfma_f32_32x32x16_f16(                  \
        xa_[0], bf[16], (f32x16)(0.f), 0, 0, 0);                            \
    f32x16 acc1_ = __builtin_amdgcn_mfma_f32_32x32x16_f16(                  \
        xa_[1], bf[16], (f32x16)(0.f), 0, 0, 0);                            \
    _Pragma("unroll") for (int kf = 0; kf < 16; ++kf) {                     \
      const char* const rp = lds + (rbase ^ (kf << 5));                     \
      const half8 a0_ = *(const half8*)(rp + (RBUF)*32768);                 \
      acc0_ = __builtin_amdgcn_mfma_f32_32x32x16_f16(a0_, bf[kf], acc0_,    \
                                                     0, 0, 0);              \
      const half8 a1_ = *(const half8*)(rp + (RBUF)*32768 + 16384);         \
      acc1_ = __builtin_amdgcn_mfma_f32_32x32x16_f16(a1_, bf[kf], acc1_,    \
                                                     0, 0, 0);              \
    }                                                                       \
    EPILOGUE(acc0_, acc1_, (RBUF) ^ 1);                                     \
  } while (0)

__global__ __launch_bounds__(512)
__attribute__((amdgpu_waves_per_eu(2, 2)))
void rnn_fused(const float* __restrict__ x, const float* __restrict__ W,
               const float* __restrict__ U, const float* __restrict__ b,
               const float* __restrict__ W1, const float* __restrict__ b1,
               float* __restrict__ out) {
  __shared__ alignas(16) h16 hbuf[2][64 * 256];  // 2 x 32 KB

  const int tid = threadIdx.x;
  const int lane = tid & 63;
  const int wave = tid >> 6;        // 0..7, owns cols [32w, 32w+32)
  const int l31 = lane & 31;
  const int q = lane >> 5;
  const bool par = l31 & 1;         // odd lane of a col pair
  const int row0 = blockIdx.x << 6; // 64 batch rows per block
  const int n = (wave << 5) + l31;  // this lane's output column

  half8 bf[17];
  load_bfrags(bf, U, W, b, n, q);

  char* const lds = (char*)hbuf;

  // XOR-separable base addresses (see header comment)
  const int rbase = (l31 << 9) ^ (q << 4) ^ (l31 << 4);
  const int wpk = (q << 11) ^ (q << 6) ^ ((int)par << 13) ^
                  ((int)par << 8) ^ ((n >> 3) << 4) ^ ((n & 6) << 1);

  const char* const xbase = (const char*)x;
  int xoff[2];
  #pragma unroll
  for (int mf = 0; mf < 2; ++mf)
    xoff[mf] = ((row0 + (mf << 5) + l31) * (T_STEPS * F_IN) +
                (T_STEPS - 1) * F_IN)
               << 2;

  // ---- s = 0 (t = 78): h0 = 0, no LDS read, writes buf1, no barrier ----
  {
    LOAD_X(lo_, hi_);
    MAKE_XA(xa_, lo_, hi_);
    f32x16 acc0_ = __builtin_amdgcn_mfma_f32_32x32x16_f16(
        xa_[0], bf[16], (f32x16)(0.f), 0, 0, 0);
    f32x16 acc1_ = __builtin_amdgcn_mfma_f32_32x32x16_f16(
        xa_[1], bf[16], (f32x16)(0.f), 0, 0, 0);
    EPILOGUE(acc0_, acc1_, 1);
  }

  // ---- s = 1..78 as 39 unrolled pairs: odd s reads buf1, even s buf0 ----
  #pragma unroll 1
  for (int sp = 0; sp < (T_STEPS - 1) / 2; ++sp) {
    STEP(1);
    STEP(0);
  }
  // last step (s=78, even) read buf0 and wrote h(final) into buf1

  // ---- final Dense(256, relu): same GEMM with W1/b1, x rows zeroed ----
  load_bfrags(bf, W1, nullptr, b1, n, q);
  half8 xaf;
  #pragma unroll
  for (int j = 0; j < 8; ++j) xaf[j] = (h16)0.f;
  if (q == 1) xaf[0] = (h16)1.f;

  f32x16 acc0 = __builtin_amdgcn_mfma_f32_32x32x16_f16(
      xaf, bf[16], (f32x16)(0.f), 0, 0, 0);
  f32x16 acc1 = __builtin_amdgcn_mfma_f32_32x32x16_f16(
      xaf, bf[16], (f32x16)(0.f), 0, 0, 0);

  __syncthreads();  // h(final) writes visible in buf1

  #pragma unroll
  for (int kf = 0; kf < 16; ++kf) {
    const char* const rp = lds + (rbase ^ (kf << 5));
    const half8 a0 = *(const half8*)(rp + 32768);
    acc0 = __builtin_amdgcn_mfma_f32_32x32x16_f16(a0, bf[kf], acc0, 0, 0, 0);
    const half8 a1 = *(const half8*)(rp + 32768 + 16384);
    acc1 = __builtin_amdgcn_mfma_f32_32x32x16_f16(a1, bf[kf], acc1, 0, 0, 0);
  }

  #pragma unroll
  for (int g = 0; g < 16; ++g) {
    const int rr = (g & 3) + ((g >> 2) << 3) + (q << 2);
    out[(size_t)(row0 + rr) * C_DIM + n] = fmaxf(acc0[g], 0.f);
    out[(size_t)(row0 + 32 + rr) * C_DIM + n] = fmaxf(acc1[g], 0.f);
  }
}

extern "C" void kernel_launch(void* const* d_in, const int* in_sizes, int n_in,
                              void* d_out, int out_size, void* d_ws,
                              size_t ws_size, hipStream_t stream) {
  const float* x  = (const float*)d_in[0];
  const float* W  = (const float*)d_in[1];
  const float* U  = (const float*)d_in[2];
  const float* b  = (const float*)d_in[3];
  const float* W1 = (const float*)d_in[4];
  const float* b1 = (const float*)d_in[5];
  float* out = (float*)d_out;

  rnn_fused<<<B_ROWS / 64, 512, 0, stream>>>(x, W, U, b, W1, b1, out);
}